// Round 1
// baseline (677.006 us; speedup 1.0000x reference)
//
#include <hip/hip_runtime.h>
#include <hip/hip_bf16.h>

#define CLS 32000
#define NVEC (CLS / 4)   // 8000 float4 per row
#define BLOCK 256

// Zero the scalar output (harness re-poisons d_out to 0xAA before every timed launch).
__global__ void zero_kernel(float* out) {
    if (threadIdx.x == 0) out[0] = 0.0f;
}

// Online-softmax merge of two (max, sumexp, argmax-index) states.
// Tie-break on equal max: smaller index (matches jnp.argmax first-occurrence).
__device__ __forceinline__ void merge_state(float& m, float& s, int& idx,
                                            float om, float os, int oi) {
    float M = fmaxf(m, om);
    float S = s * __expf(m - M) + os * __expf(om - M);
    int I;
    if (m > om)      I = idx;
    else if (om > m) I = oi;
    else             I = (idx < oi) ? idx : oi;
    m = M; s = S; idx = I;
}

__global__ __launch_bounds__(BLOCK) void focal_loss_kernel(
    const float* __restrict__ input,    // [N, CLS] fp32
    const int*   __restrict__ target,   // [N]
    const float* __restrict__ weight,   // [CLS]
    const float* __restrict__ gammap,   // [1]
    float* __restrict__ out)            // [1]
{
    const int row = blockIdx.x;
    const size_t base = (size_t)row * CLS;
    const float4* __restrict__ rp4 = (const float4*)(input + base);
    const int tid = threadIdx.x;

    // Per-thread online softmax state. -FLT_MAX (not -inf) so the merge
    // of two untouched states is NaN-free; every thread processes >=124
    // elements here anyway so m is always finite by reduction time.
    float m = -3.402823466e38f;
    float s = 0.0f;
    int   idx = 0x7fffffff;

    for (int i = tid; i < NVEC; i += BLOCK) {
        float4 v = rp4[i];
#define PROC(XV, J)                                   \
        {                                             \
            float xv = (XV);                          \
            if (xv > m) {                             \
                s = s * __expf(m - xv) + 1.0f;        \
                m = xv;                               \
                idx = 4 * i + (J);                    \
            } else {                                  \
                s += __expf(xv - m);                  \
            }                                         \
        }
        PROC(v.x, 0)
        PROC(v.y, 1)
        PROC(v.z, 2)
        PROC(v.w, 3)
#undef PROC
    }

    // Wave(64)-level butterfly-ish reduce via shfl_down.
    for (int off = 32; off > 0; off >>= 1) {
        float om = __shfl_down(m, off);
        float os = __shfl_down(s, off);
        int   oi = __shfl_down(idx, off);
        merge_state(m, s, idx, om, os, oi);
    }

    // Cross-wave combine (4 waves per block).
    __shared__ float sm[BLOCK / 64];
    __shared__ float ss[BLOCK / 64];
    __shared__ int   si[BLOCK / 64];
    const int wave = tid >> 6;
    if ((tid & 63) == 0) { sm[wave] = m; ss[wave] = s; si[wave] = idx; }
    __syncthreads();

    if (tid == 0) {
        for (int w = 1; w < BLOCK / 64; ++w)
            merge_state(m, s, idx, sm[w], ss[w], si[w]);

        const int   t  = target[row];
        const float xt = input[base + (size_t)t];
        const float logp_t = xt - m - __logf(s);   // log p_target
        const float p_t    = __expf(logp_t);
        const float g      = gammap[0];
        const float w      = weight[idx];          // weight[argmax(input_row)]
        const float loss   = w * __powf(1.0f - p_t, g) * (-logp_t);
        atomicAdd(out, loss);
    }
}

extern "C" void kernel_launch(void* const* d_in, const int* in_sizes, int n_in,
                              void* d_out, int out_size, void* d_ws, size_t ws_size,
                              hipStream_t stream) {
    const float* input  = (const float*)d_in[0];
    const int*   target = (const int*)  d_in[1];
    const float* weight = (const float*)d_in[2];
    const float* gammap = (const float*)d_in[3];
    float* out = (float*)d_out;

    const int N = in_sizes[0] / CLS;   // 4096

    zero_kernel<<<1, 64, 0, stream>>>(out);
    focal_loss_kernel<<<N, BLOCK, 0, stream>>>(input, target, weight, gammap, out);
}